// Round 21
// baseline (175.842 us; speedup 1.0000x reference)
//
#include <hip/hip_runtime.h>
#include <hip/hip_bf16.h>

typedef __hip_bfloat16 bf16;
typedef unsigned char u8;
typedef __attribute__((ext_vector_type(8))) __bf16 bf16x8;
typedef __attribute__((ext_vector_type(4))) float f32x4;
typedef __attribute__((ext_vector_type(2))) float f32x2;

__device__ __forceinline__ void gld_lds16(const void* g, void* l) {
  __builtin_amdgcn_global_load_lds((const __attribute__((address_space(1))) void*)g,
                                   (__attribute__((address_space(3))) void*)l, 16, 0, 0);
}
__device__ __forceinline__ f32x2 pk_mul(f32x2 a, f32x2 b) {
  f32x2 d;
  asm("v_pk_mul_f32 %0, %1, %2" : "=v"(d) : "v"(a), "v"(b));
  return d;
}
__device__ __forceinline__ f32x2 pk_fma(f32x2 a, f32x2 b, f32x2 c) {
  f32x2 d;
  asm("v_pk_fma_f32 %0, %1, %2, %3" : "=v"(d) : "v"(a), "v"(b), "v"(c));
  return d;
}

// ---- setup: Wm fold (blocks 0..431, FIRST) | weight transposes (432..2447) | LN1 (2448..6543)
__global__ __launch_bounds__(256) void setup_k(
    const float* __restrict__ x, const float* __restrict__ gamma1, const float* __restrict__ beta1,
    const float* __restrict__ wq, const float* __restrict__ wk,
    const float* __restrict__ wv, const float* __restrict__ wo,
    const float* __restrict__ post_w, const float* __restrict__ w1, const float* __restrict__ w2,
    bf16* __restrict__ nb, bf16* __restrict__ WqkvT,
    bf16* __restrict__ w1f, bf16* __restrict__ w2f)
{
  const int bid = blockIdx.x;
  if (bid < 432) {
    const int j = bid * 256 + threadIdx.x;
    const int dd = j % 192;
    const int r = j / 192;
    const int h = r / 192, din = r % 192;
    float acc = 0.f;
    #pragma unroll
    for (int g2 = 0; g2 < 3; ++g2) {
      const float pw = post_w[h*3 + g2];
      const float* wvp = wv + (size_t)din*576 + g2*192;
      const float* wop = wo + (size_t)(g2*192)*192 + dd;
      float s0 = 0.f, s1 = 0.f, s2 = 0.f, s3 = 0.f;
      for (int kd = 0; kd < 192; kd += 4) {
        s0 += wvp[kd]     * wop[(size_t)kd*192];
        s1 += wvp[kd + 1] * wop[(size_t)(kd + 1)*192];
        s2 += wvp[kd + 2] * wop[(size_t)(kd + 2)*192];
        s3 += wvp[kd + 3] * wop[(size_t)(kd + 3)*192];
      }
      acc += pw * ((s0 + s1) + (s2 + s3));
    }
    WqkvT[(size_t)(1152 + h*192 + dd)*192 + din] = __float2bfloat16(acc);
    return;
  }
  if (bid < 2448) {
    int i = (bid - 432) * 256 + threadIdx.x;
    if (i < 221184) {
      int n = i / 192, d = i % 192;
      int sel = n / 576, c = n % 576, h = c / 192, kd = c % 192;
      const float* w = (sel == 0) ? wq : wk;
      WqkvT[i] = __float2bfloat16(w[(d*3 + h)*192 + kd]);
      return;
    }
    i -= 221184;
    if (i < 147456) {
      int j = i / 192, k = i % 192;
      int c = j >> 6, jc = j & 63, jb = jc >> 4, j15 = jc & 15;
      int kq = k >> 5, sl = (k & 31) >> 3, e7 = k & 7;
      w1f[(size_t)(((c*6 + kq)*4 + jb)*512) + (j15 + (sl << 4))*8 + e7] =
          __float2bfloat16(w1[(size_t)k*768 + j]);
      return;
    }
    i -= 147456;
    {
      int j = i / 192, d = i % 192;
      int c = j >> 6, ks = (j >> 5) & 1, l4 = (j >> 3) & 3, e = j & 7;
      int dn = d >> 4, l15 = d & 15;
      w2f[(size_t)((((c*2 + ks)*12 + dn)*64) + l4*16 + l15)*8 + e] =
          __float2bfloat16(w2[(size_t)j*192 + d]);
    }
    return;
  }
  {
    int row = (bid - 2448) * 4 + (threadIdx.x >> 6);
    int lane = threadIdx.x & 63;
    const float* xr = x + (size_t)row * 192;
    float v0 = xr[lane], v1 = xr[lane + 64], v2 = xr[lane + 128];
    float s = v0 + v1 + v2;
    #pragma unroll
    for (int o = 32; o; o >>= 1) s += __shfl_xor(s, o);
    float mu = s * (1.f / 192.f);
    float d0 = v0 - mu, d1 = v1 - mu, d2 = v2 - mu;
    float q = d0*d0 + d1*d1 + d2*d2;
    #pragma unroll
    for (int o = 32; o; o >>= 1) q += __shfl_xor(q, o);
    float rs = rsqrtf(q * (1.f / 192.f) + 1e-3f);
    bf16* orow = nb + (size_t)row * 192;
    orow[lane]       = __float2bfloat16(d0*rs*gamma1[lane]       + beta1[lane]);
    orow[lane + 64]  = __float2bfloat16(d1*rs*gamma1[lane + 64]  + beta1[lane + 64]);
    orow[lane + 128] = __float2bfloat16(d2*rs*gamma1[lane + 128] + beta1[lane + 128]);
  }
}

// ---------------- QKV GEMM, 128x64 tile, 4 waves. Col-blocks are uniformly q/k/MT ----------
__global__ __launch_bounds__(256) void gemm_qkv(
    const bf16* __restrict__ A, const bf16* __restrict__ BT,
    u8* __restrict__ q_out, u8* __restrict__ k_out, u8* __restrict__ mt_out)
{
  const int K = 192;
  const int tid = threadIdx.x, lane = tid & 63, wid = tid >> 6;
  const int l15 = lane & 15, l4 = lane >> 4;
  const int wm = wid >> 1, wn = wid & 1;
  const int row0 = blockIdx.y * 128, col0 = blockIdx.x * 64;
  const int sel0 = col0 / 576;                 // block-uniform: 0=q, 1=k, 2=MT
  __shared__ __align__(16) bf16 As[2][128 * 32];
  __shared__ __align__(16) bf16 Bs[2][64 * 32];
  f32x4 acc[4][2] = {};

#define STAGE(buf_, kt_) do { \
    const bf16* Ab_ = A + (size_t)row0 * K + (kt_) * 32; \
    int c0_ = tid, r0_ = c0_ >> 2, cc0_ = (c0_ & 3) << 3; \
    gld_lds16(Ab_ + (size_t)r0_ * K + cc0_, &As[buf_][c0_ * 8]); \
    int c1_ = tid + 256, r1_ = c1_ >> 2, cc1_ = (c1_ & 3) << 3; \
    gld_lds16(Ab_ + (size_t)r1_ * K + cc1_, &As[buf_][c1_ * 8]); \
    const bf16* Bb_ = BT + (size_t)col0 * K + (kt_) * 32; \
    gld_lds16(Bb_ + (size_t)(tid >> 2) * K + ((tid & 3) << 3), &Bs[buf_][tid * 8]); \
  } while (0)

  STAGE(0, 0);
  for (int kt = 0; kt < 6; ++kt) {
    __syncthreads();
    const int buf = kt & 1;
    if (kt + 1 < 6) STAGE(buf ^ 1, kt + 1);
    const int koff = l4 * 8;
    bf16x8 af[4], bfr[2];
    #pragma unroll
    for (int m = 0; m < 4; ++m)
      af[m] = *(const bf16x8*)&As[buf][(wm*64 + m*16 + l15)*32 + koff];
    #pragma unroll
    for (int n = 0; n < 2; ++n)
      bfr[n] = *(const bf16x8*)&Bs[buf][(wn*32 + n*16 + l15)*32 + koff];
    if (sel0 < 2) {
      #pragma unroll
      for (int m = 0; m < 4; ++m)
        #pragma unroll
        for (int n = 0; n < 2; ++n)
          acc[m][n] = __builtin_amdgcn_mfma_f32_16x16x32_bf16(bfr[n], af[m], acc[m][n], 0, 0, 0);
    } else {
      #pragma unroll
      for (int m = 0; m < 4; ++m)
        #pragma unroll
        for (int n = 0; n < 2; ++n)
          acc[m][n] = __builtin_amdgcn_mfma_f32_16x16x32_bf16(af[m], bfr[n], acc[m][n], 0, 0, 0);
    }
  }
#undef STAGE

  if (sel0 < 2) {
    u8* dst = (sel0 == 0) ? q_out : k_out;
    #pragma unroll
    for (int m = 0; m < 4; ++m) {
      const int t = row0 + wm*64 + m*16 + l15;
      const int b = t >> 11, t2 = t & 2047;
      #pragma unroll
      for (int n = 0; n < 2; ++n) {
        const int c2 = (col0 - sel0*576) + wn*32 + n*16 + l4*4;
        const int h = c2 / 192, kd = c2 % 192;
        int pk = __builtin_amdgcn_cvt_pk_fp8_f32(acc[m][n][0], acc[m][n][1], 0, false);
        pk = __builtin_amdgcn_cvt_pk_fp8_f32(acc[m][n][2], acc[m][n][3], pk, true);
        const size_t fo = ((((size_t)b*64 + (t2>>5))*3 + h)*6 + (kd>>5))*1024
                        + (((t2>>4)&1))*512
                        + (((t2&15) + (((kd>>3)&3)<<4))<<3) + (kd&7);
        *(unsigned*)&dst[fo] = (unsigned)pk;
      }
    }
  } else {
    const int rbase = row0 + wm * 64;
    const int cbase = col0 + wn * 32;
    #pragma unroll
    for (int m = 0; m < 4; ++m) {
      #pragma unroll
      for (int n = 0; n < 2; ++n) {
        const int col = cbase + n*16 + l15;
        const int rtop = rbase + m*16 + (l4 << 2);
        const int b = rtop >> 11, t_ = rtop & 2047;
        const int c2 = col % 576;
        const int h = c2 / 192, kd = c2 % 192;
        int pk = __builtin_amdgcn_cvt_pk_fp8_f32(acc[m][n][0], acc[m][n][1], 0, false);
        pk = __builtin_amdgcn_cvt_pk_fp8_f32(acc[m][n][2], acc[m][n][3], pk, true);
        const size_t fo = ((((size_t)b*64 + (t_>>5))*3 + h)*12 + (kd>>4))*512
                        + (((kd&15) + (((t_>>3)&3)<<4))<<3) + (t_&4);
        *(unsigned*)&mt_out[fo] = (unsigned)pk;
      }
    }
  }
}

// ------- attention core, 2-way s-split: grid 1024 = (tt,sh)x8b, 32 steps, 3 blocks/CU -------
// Writes bf16 per-head PV partials Opart[bid][g][32][192] and L sums Lpart[bid][g][32].
__global__ __launch_bounds__(256, 2) void attn_k(
    const u8* __restrict__ q, const u8* __restrict__ kf,
    const u8* __restrict__ MT, const float* __restrict__ pre_w,
    bf16* __restrict__ Opart, float* __restrict__ Lpart)
{
  const int tid = threadIdx.x, lane = tid & 63, wv = tid >> 6;
  const int l15 = lane & 15, l4 = lane >> 4;
  const int tq = wv & 1, sq = wv >> 1;
  const int bid = blockIdx.x;
  const int b = bid & 7;                 // XCD-local batch
  const int tt = (bid >> 3) >> 1;
  const int sh = (bid >> 3) & 1;         // s-half

  __shared__ __align__(16) u8 S[43008];  // Ks 2x18432 @0, Ps 2x3072 @36864
  __shared__ float rlPart[2][3][32];
  u8* KsP = S;
  u8* PsP = S + 36864;

  const u8* qfb = q + ((size_t)b*64 + tt) * 18432;
  long qf[3][6];
  #pragma unroll
  for (int h = 0; h < 3; ++h)
    #pragma unroll
    for (int kq = 0; kq < 6; ++kq)
      qf[h][kq] = *(const long*)(qfb + ((h*6 + kq)*2 + tq)*512 + lane*8);

  f32x2 pwf2[9];
  #pragma unroll
  for (int i = 0; i < 9; ++i) {
    const float v = pre_w[i] * 0.07216878364870323f * 1.44269504088896f;
    pwf2[i][0] = v; pwf2[i][1] = v;
  }

  f32x4 acc[3][2][3] = {};
  float sgacc[3] = {0.f, 0.f, 0.f};
  const int trow = tq*16 + l15;
  const int psw = (l15 >> 2) & 3;
  const int pwr = (((sq*2 + (l4 >> 1)) ^ psw) << 3) + ((l4 & 1) << 2);
  const int prd = (l4 ^ psw) << 3;

  const u8* kfb = kf + ((size_t)b*64 + sh*32) * 18432;
  const u8* mtb = MT + ((size_t)b*64 + sh*32) * 18432;

#define STAGEK(buf_, st_) do { \
    const u8* kb_ = kfb + (size_t)(st_) * 18432; \
    _Pragma("unroll") \
    for (int i_ = 0; i_ < 5; ++i_) { \
      const int L_ = i_ * 256 + tid; \
      if (L_ < 1152) gld_lds16(kb_ + L_*16, KsP + (buf_)*18432 + L_*16); \
    } \
  } while (0)

#define LOADMF(MF_, st_) do { \
    const u8* mb_ = mtb + (size_t)(st_) * 18432 + wv*3*512 + lane*8; \
    _Pragma("unroll") \
    for (int g_ = 0; g_ < 3; ++g_) \
      _Pragma("unroll") \
      for (int n_ = 0; n_ < 3; ++n_) \
        MF_[g_][n_] = *(const long*)(mb_ + (g_*12 + n_)*512); \
  } while (0)

#define PV(stm1_, MF_) do { \
    const int bp_ = (stm1_) & 1; \
    __builtin_amdgcn_s_setprio(1); \
    _Pragma("unroll") \
    for (int g_ = 0; g_ < 3; ++g_) \
      _Pragma("unroll") \
      for (int m_ = 0; m_ < 2; ++m_) { \
        const long pf_ = *(const long*)(PsP + bp_*3072 + g_*1024 + (m_*16 + l15)*32 + prd); \
        _Pragma("unroll") \
        for (int n_ = 0; n_ < 3; ++n_) \
          acc[g_][m_][n_] = __builtin_amdgcn_mfma_f32_16x16x32_fp8_fp8(pf_, MF_[g_][n_], acc[g_][m_][n_], 0, 0, 0); \
      } \
    __builtin_amdgcn_s_setprio(0); \
  } while (0)

#define QKSM(st_) do { \
    const int bq_ = (st_) & 1; \
    f32x4 sacc0 = {}, sacc1 = {}, sacc2 = {}; \
    __builtin_amdgcn_s_setprio(1); \
    _Pragma("unroll") \
    for (int kq_ = 0; kq_ < 6; ++kq_) { \
      const long kf0_ = *(const long*)(KsP + bq_*18432 + (((0*6 + kq_)*2 + sq)*512) + lane*8); \
      sacc0 = __builtin_amdgcn_mfma_f32_16x16x32_fp8_fp8(kf0_, qf[0][kq_], sacc0, 0, 0, 0); \
      const long kf1_ = *(const long*)(KsP + bq_*18432 + (((1*6 + kq_)*2 + sq)*512) + lane*8); \
      sacc1 = __builtin_amdgcn_mfma_f32_16x16x32_fp8_fp8(kf1_, qf[1][kq_], sacc1, 0, 0, 0); \
      const long kf2_ = *(const long*)(KsP + bq_*18432 + (((2*6 + kq_)*2 + sq)*512) + lane*8); \
      sacc2 = __builtin_amdgcn_mfma_f32_16x16x32_fp8_fp8(kf2_, qf[2][kq_], sacc2, 0, 0, 0); \
    } \
    __builtin_amdgcn_s_setprio(0); \
    f32x2 p0a = {sacc0[0], sacc0[1]}, p0b = {sacc0[2], sacc0[3]}; \
    f32x2 p1a = {sacc1[0], sacc1[1]}, p1b = {sacc1[2], sacc1[3]}; \
    f32x2 p2a = {sacc2[0], sacc2[1]}, p2b = {sacc2[2], sacc2[3]}; \
    _Pragma("unroll") \
    for (int g_ = 0; g_ < 3; ++g_) { \
      f32x2 va = pk_mul(p0a, pwf2[g_]); \
      va = pk_fma(p1a, pwf2[3+g_], va); \
      va = pk_fma(p2a, pwf2[6+g_], va); \
      f32x2 vb = pk_mul(p0b, pwf2[g_]); \
      vb = pk_fma(p1b, pwf2[3+g_], vb); \
      vb = pk_fma(p2b, pwf2[6+g_], vb); \
      float e0_ = exp2f(va[0]), e1_ = exp2f(va[1]); \
      float e2_ = exp2f(vb[0]), e3_ = exp2f(vb[1]); \
      sgacc[g_] += (e0_ + e1_) + (e2_ + e3_); \
      int pk_ = __builtin_amdgcn_cvt_pk_fp8_f32(e0_, e1_, 0, false); \
      pk_ = __builtin_amdgcn_cvt_pk_fp8_f32(e2_, e3_, pk_, true); \
      *(unsigned*)(PsP + bq_*3072 + g_*1024 + trow*32 + pwr) = (unsigned)pk_; \
    } \
  } while (0)

  long mfA[3][3], mfB[3][3];

  STAGEK(0, 0);
  __syncthreads();
  STAGEK(1, 1);
  LOADMF(mfA, 0);
  QKSM(0);
  for (int st = 1; st < 31; st += 2) {
    __syncthreads();
    STAGEK((st + 1) & 1, st + 1);
    LOADMF(mfB, st);
    PV(st - 1, mfA);
    QKSM(st);
    __syncthreads();
    if (st + 2 < 32) STAGEK((st + 2) & 1, st + 2);
    LOADMF(mfA, st + 1);
    PV(st, mfB);
    QKSM(st + 1);
  }
  __syncthreads();
  LOADMF(mfB, 31);
  PV(30, mfA);
  QKSM(31);
  __syncthreads();
  PV(31, mfB);
  #pragma unroll
  for (int g = 0; g < 3; ++g) {
    float s = sgacc[g];
    s += __shfl_xor(s, 16);
    s += __shfl_xor(s, 32);
    if (l4 == 0) rlPart[sq][g][trow] = s;
  }
  __syncthreads();

  // L partial sums (per block)
  if (tid < 96) {
    const int g = tid >> 5, row = tid & 31;
    Lpart[(size_t)bid*96 + g*32 + row] = rlPart[0][g][row] + rlPart[1][g][row];
  }
  // O partials (bf16, per head g, unnormalized)
  bf16* op = Opart + (size_t)bid * 3 * 32 * 192;
  #pragma unroll
  for (int g = 0; g < 3; ++g)
    #pragma unroll
    for (int m = 0; m < 2; ++m)
      #pragma unroll
      for (int n = 0; n < 3; ++n) {
        const int d = wv*48 + n*16 + l15;
        #pragma unroll
        for (int j = 0; j < 4; ++j)
          op[(g*32 + m*16 + l4*4 + j)*192 + d] = __float2bfloat16(acc[g][m][n][j]);
      }
#undef STAGEK
#undef LOADMF
#undef PV
#undef QKSM
}

// ------- combine + LN2 + MLP: out = resid + gelu(LN2(resid)@w1+b1)@w2 + b2 -------
// resid = x + sum_g (Opart_h0 + Opart_h1)_g / (L_h0 + L_h1)_g
__global__ __launch_bounds__(256, 2) void comb_k(
    const bf16* __restrict__ Opart, const float* __restrict__ Lpart,
    const float* __restrict__ x, const float* __restrict__ gamma2,
    const float* __restrict__ beta2, const bf16* __restrict__ w1f,
    const bf16* __restrict__ w2f, const float* __restrict__ b1,
    const float* __restrict__ b2, float* __restrict__ out)
{
  const int tid = threadIdx.x, lane = tid & 63, wv = tid >> 6;
  const int l15 = lane & 15, l4 = lane >> 4;
  const int cid = blockIdx.x;
  const int b = cid & 7;                 // XCD-local batch
  const int tt = cid >> 3;
  const int t0 = tt * 32;

  // LDS: N2f 12288 @0, Bs dbuf 2x24576 @12288, Hf dbuf 2x4096 @61440
  __shared__ __align__(16) u8 S[69632];
  __shared__ float Ls[3][32];
  __shared__ float lnS[4][32][2];
  bf16* N2 = (bf16*)S;
  bf16* BsP = (bf16*)(S + 12288);
  bf16* HfP = (bf16*)(S + 61440);

  const int bid0 = ((tt*2 + 0) << 3) | b;
  const int bid1 = ((tt*2 + 1) << 3) | b;
  const bf16* op0 = Opart + (size_t)bid0 * 3 * 32 * 192;
  const bf16* op1 = Opart + (size_t)bid1 * 3 * 32 * 192;

#define STAGEB(buf_, c_) do { \
    const u8* wsrc_ = (const u8*)w1f + (size_t)(c_) * 24576; \
    _Pragma("unroll") \
    for (int i_ = 0; i_ < 6; ++i_) { \
      const int L_ = i_ * 256 + tid; \
      gld_lds16(wsrc_ + L_*16, (u8*)BsP + (buf_)*24576 + L_*16); \
    } \
  } while (0)

#define LOADWF(WF_, c_) do { \
    _Pragma("unroll") \
    for (int n_ = 0; n_ < 3; ++n_) \
      _Pragma("unroll") \
      for (int ks_ = 0; ks_ < 2; ++ks_) \
        WF_[n_][ks_] = *(const bf16x8*)(w2f + (size_t)(((((c_)*2 + ks_)*12) + wv*3 + n_)*64 + lane)*8); \
  } while (0)

  const int wmm = wv >> 1, wnn = wv & 1;

#define MGEMM1(c_) do { \
    f32x4 sacc[2] = {}; \
    _Pragma("unroll") \
    for (int kq_ = 0; kq_ < 6; ++kq_) { \
      const bf16x8 af_ = *(const bf16x8*)&N2[((kq_*2 + wmm)*512) + lane*8]; \
      _Pragma("unroll") \
      for (int n_ = 0; n_ < 2; ++n_) { \
        const bf16x8 bfr_ = *(const bf16x8*)&BsP[((c_)&1)*12288 + ((kq_*4 + wnn*2 + n_)*512) + lane*8]; \
        sacc[n_] = __builtin_amdgcn_mfma_f32_16x16x32_bf16(af_, bfr_, sacc[n_], 0, 0, 0); \
      } \
    } \
    _Pragma("unroll") \
    for (int n_ = 0; n_ < 2; ++n_) { \
      const int jc_ = wnn*32 + n_*16 + l15; \
      const float bv_ = b1[(c_)*64 + jc_]; \
      const int sl_ = (jc_ & 31) >> 3, e7_ = jc_ & 7; \
      _Pragma("unroll") \
      for (int jr_ = 0; jr_ < 4; ++jr_) { \
        const int r15_ = l4*4 + jr_; \
        const float u_ = sacc[n_][jr_] + bv_; \
        const float g_ = 0.5f * u_ * (1.f + erff(u_ * 0.70710678118654752f)); \
        HfP[((c_)&1)*2048 + ((wnn*2 + wmm)*512) + ((r15_ + (sl_ << 4)) << 3) + e7_] = __float2bfloat16(g_); \
      } \
    } \
  } while (0)

#define MGEMM2(WF_, hbuf_) do { \
    _Pragma("unroll") \
    for (int ks_ = 0; ks_ < 2; ++ks_) { \
      bf16x8 ha_[2]; \
      _Pragma("unroll") \
      for (int m_ = 0; m_ < 2; ++m_) \
        ha_[m_] = *(const bf16x8*)&HfP[(hbuf_)*2048 + ((ks_*2 + m_)*512) + lane*8]; \
      _Pragma("unroll") \
      for (int m_ = 0; m_ < 2; ++m_) \
        _Pragma("unroll") \
        for (int n_ = 0; n_ < 3; ++n_) \
          macc[m_][n_] = __builtin_amdgcn_mfma_f32_16x16x32_bf16(ha_[m_], WF_[n_][ks_], macc[m_][n_], 0, 0, 0); \
    } \
  } while (0)

  // L sums -> LDS
  if (tid < 96) {
    const int g = tid >> 5, row = tid & 31;
    Ls[g][row] = Lpart[(size_t)bid0*96 + g*32 + row] + Lpart[(size_t)bid1*96 + g*32 + row];
  }
  __syncthreads();

  // resid = x + combined attention (regs), LN2 partials
  float ovv[2][3][4];
  #pragma unroll
  for (int m = 0; m < 2; ++m) {
    #pragma unroll
    for (int j = 0; j < 4; ++j) {
      const int row = m*16 + l4*4 + j;
      float rlv[3];
      #pragma unroll
      for (int g = 0; g < 3; ++g) rlv[g] = 1.f / Ls[g][row];
      float s = 0.f, ss = 0.f;
      #pragma unroll
      for (int n = 0; n < 3; ++n) {
        const int d = wv*48 + n*16 + l15;
        const size_t pidx = (size_t)row*192 + d;
        float ov = x[((size_t)b*2048 + t0 + row)*192 + d];
        #pragma unroll
        for (int g = 0; g < 3; ++g)
          ov += rlv[g] * (__bfloat162float(op0[g*32*192 + pidx]) +
                          __bfloat162float(op1[g*32*192 + pidx]));
        ovv[m][n][j] = ov;
        s += ov; ss += ov*ov;
      }
      #pragma unroll
      for (int o = 1; o < 16; o <<= 1) { s += __shfl_xor(s, o); ss += __shfl_xor(ss, o); }
      if (l15 == 0) { lnS[wv][row][0] = s; lnS[wv][row][1] = ss; }
    }
  }
  STAGEB(0, 0);
  __syncthreads();

  // LN2 -> N2 (frag-linear)
  {
    float gmL[3], btL[3];
    #pragma unroll
    for (int n = 0; n < 3; ++n) {
      const int d = wv*48 + n*16 + l15;
      gmL[n] = gamma2[d]; btL[n] = beta2[d];
    }
    #pragma unroll
    for (int m = 0; m < 2; ++m) {
      #pragma unroll
      for (int j = 0; j < 4; ++j) {
        const int row = m*16 + l4*4 + j;
        const float ts  = lnS[0][row][0] + lnS[1][row][0] + lnS[2][row][0] + lnS[3][row][0];
        const float tss = lnS[0][row][1] + lnS[1][row][1] + lnS[2][row][1] + lnS[3][row][1];
        const float mu = ts * (1.f / 192.f);
        const float rs = rsqrtf(tss * (1.f / 192.f) - mu*mu + 1e-3f);
        #pragma unroll
        for (int n = 0; n < 3; ++n) {
          const int d = wv*48 + n*16 + l15;
          N2[(((d>>5)*2 + m)*512) + (((row&15) + (((d&31)>>3)<<4))<<3) + (d&7)] =
              __float2bfloat16((ovv[m][n][j] - mu) * rs * gmL[n] + btL[n]);
        }
      }
    }
  }
  __syncthreads();   // N2 + Bs[0] ready

  // MLP pipelined, 1 barrier/chunk
  f32x4 macc[2][3] = {};
  bf16x8 wfA[3][2], wfB[3][2];
  STAGEB(1, 1);
  LOADWF(wfA, 0);
  MGEMM1(0);
  __syncthreads();
  for (int c = 1; c < 11; c += 2) {
    STAGEB((c + 1) & 1, c + 1);
    LOADWF(wfB, c);
    MGEMM2(wfA, (c - 1) & 1);
    MGEMM1(c);
    __syncthreads();
    if (c + 2 < 12) STAGEB((c + 2) & 1, c + 2);
    LOADWF(wfA, c + 1);
    MGEMM2(wfB, c & 1);
    MGEMM1(c + 1);
    __syncthreads();
  }
  LOADWF(wfB, 11);
  MGEMM2(wfA, 0);
  MGEMM1(11);
  __syncthreads();
  MGEMM2(wfB, 1);

  #pragma unroll
  for (int n = 0; n < 3; ++n) {
    const int d = wv*48 + n*16 + l15;
    const float b2v = b2[d];
    #pragma unroll
    for (int m = 0; m < 2; ++m) {
      #pragma unroll
      for (int jr = 0; jr < 4; ++jr) {
        const int row = m*16 + l4*4 + jr;
        const size_t idx = ((size_t)b*2048 + t0 + row)*192 + d;
        out[idx] = ovv[m][n][jr] + macc[m][n][jr] + b2v;
      }
    }
  }
#undef STAGEB
#undef LOADWF
#undef MGEMM1
#undef MGEMM2
}

// ---------------- host launcher ----------------
extern "C" void kernel_launch(void* const* d_in, const int* in_sizes, int n_in,
                              void* d_out, int out_size, void* d_ws, size_t ws_size,
                              hipStream_t stream)
{
  (void)in_sizes; (void)n_in; (void)out_size; (void)ws_size;
  const float* x      = (const float*)d_in[0];
  const float* gamma1 = (const float*)d_in[1];
  const float* beta1  = (const float*)d_in[2];
  const float* gamma2 = (const float*)d_in[3];
  const float* beta2  = (const float*)d_in[4];
  const float* wq     = (const float*)d_in[5];
  const float* wk     = (const float*)d_in[6];
  const float* wv     = (const float*)d_in[7];
  const float* wo     = (const float*)d_in[8];
  const float* pre_w  = (const float*)d_in[9];
  const float* post_w = (const float*)d_in[10];
  const float* w1     = (const float*)d_in[11];
  const float* b1     = (const float*)d_in[12];
  const float* w2     = (const float*)d_in[13];
  const float* b2     = (const float*)d_in[14];
  float* out = (float*)d_out;

  uint8_t* base = (uint8_t*)d_ws;
  size_t off = 0;
  auto alloc = [&](size_t bytes) {
    uint8_t* r = base + off; off += (bytes + 255) & ~(size_t)255; return r;
  };
  bf16* nb      = (bf16*)alloc((size_t)16384 * 192 * 2);    // n1
  u8*   qb      = (u8*)alloc((size_t)9437184);              // Q frag
  u8*   kb      = (u8*)alloc((size_t)9437184);              // K frag
  u8*   MTslab  = (u8*)alloc((size_t)9437184);              // MT frag
  bf16* WqkvT   = (bf16*)alloc((size_t)331776 * 2);         // rows 0..1151 q,k; 1152..1727 Wm
  bf16* w1f     = (bf16*)alloc((size_t)147456 * 2);         // w1 fragment-linear
  bf16* w2f     = (bf16*)alloc((size_t)147456 * 2);         // w2 fragment-linear
  bf16* Opart   = (bf16*)alloc((size_t)1024 * 3 * 32 * 192 * 2);  // PV partials
  float* Lpart  = (float*)alloc((size_t)1024 * 96 * 4);           // L partials

  setup_k<<<6544, 256, 0, stream>>>(x, gamma1, beta1, wq, wk, wv, wo, post_w, w1, w2,
                                    nb, WqkvT, w1f, w2f);
  gemm_qkv<<<dim3(27, 128, 1), 256, 0, stream>>>(nb, WqkvT, qb, kb, MTslab);
  attn_k<<<1024, 256, 0, stream>>>(qb, kb, MTslab, pre_w, Opart, Lpart);
  comb_k<<<512, 256, 0, stream>>>(Opart, Lpart, x, gamma2, beta2,
                                  w1f, w2f, b1, b2, out);
}

// Round 22
// 161.320 us; speedup vs baseline: 1.0900x; 1.0900x over previous
//
#include <hip/hip_runtime.h>
#include <hip/hip_bf16.h>

typedef __hip_bfloat16 bf16;
typedef unsigned char u8;
typedef __attribute__((ext_vector_type(8))) __bf16 bf16x8;
typedef __attribute__((ext_vector_type(4))) float f32x4;
typedef __attribute__((ext_vector_type(2))) float f32x2;

__device__ __forceinline__ void gld_lds16(const void* g, void* l) {
  __builtin_amdgcn_global_load_lds((const __attribute__((address_space(1))) void*)g,
                                   (__attribute__((address_space(3))) void*)l, 16, 0, 0);
}
__device__ __forceinline__ u8 f2e4m3(float v) {
  return (u8)(__builtin_amdgcn_cvt_pk_fp8_f32(v, 0.f, 0, false) & 0xff);
}
__device__ __forceinline__ f32x2 pk_mul(f32x2 a, f32x2 b) {
  f32x2 d;
  asm("v_pk_mul_f32 %0, %1, %2" : "=v"(d) : "v"(a), "v"(b));
  return d;
}
__device__ __forceinline__ f32x2 pk_fma(f32x2 a, f32x2 b, f32x2 c) {
  f32x2 d;
  asm("v_pk_fma_f32 %0, %1, %2, %3" : "=v"(d) : "v"(a), "v"(b), "v"(c));
  return d;
}

// ---- setup: Wm fold (blocks 0..431, FIRST) | weight transposes (432..2447) | LN1 (2448..6543)
__global__ __launch_bounds__(256) void setup_k(
    const float* __restrict__ x, const float* __restrict__ gamma1, const float* __restrict__ beta1,
    const float* __restrict__ wq, const float* __restrict__ wk,
    const float* __restrict__ wv, const float* __restrict__ wo,
    const float* __restrict__ post_w, const float* __restrict__ w1, const float* __restrict__ w2,
    bf16* __restrict__ nb, bf16* __restrict__ WqkvT,
    bf16* __restrict__ w1f, bf16* __restrict__ w2f)
{
  const int bid = blockIdx.x;
  if (bid < 432) {
    const int j = bid * 256 + threadIdx.x;
    const int dd = j % 192;
    const int r = j / 192;
    const int h = r / 192, din = r % 192;
    float acc = 0.f;
    #pragma unroll
    for (int g2 = 0; g2 < 3; ++g2) {
      const float pw = post_w[h*3 + g2];
      const float* wvp = wv + (size_t)din*576 + g2*192;
      const float* wop = wo + (size_t)(g2*192)*192 + dd;
      float s0 = 0.f, s1 = 0.f, s2 = 0.f, s3 = 0.f;
      for (int kd = 0; kd < 192; kd += 4) {
        s0 += wvp[kd]     * wop[(size_t)kd*192];
        s1 += wvp[kd + 1] * wop[(size_t)(kd + 1)*192];
        s2 += wvp[kd + 2] * wop[(size_t)(kd + 2)*192];
        s3 += wvp[kd + 3] * wop[(size_t)(kd + 3)*192];
      }
      acc += pw * ((s0 + s1) + (s2 + s3));
    }
    WqkvT[(size_t)(1152 + h*192 + dd)*192 + din] = __float2bfloat16(acc);
    return;
  }
  if (bid < 2448) {
    int i = (bid - 432) * 256 + threadIdx.x;
    if (i < 221184) {
      int n = i / 192, d = i % 192;
      int sel = n / 576, c = n % 576, h = c / 192, kd = c % 192;
      const float* w = (sel == 0) ? wq : wk;
      WqkvT[i] = __float2bfloat16(w[(d*3 + h)*192 + kd]);
      return;
    }
    i -= 221184;
    if (i < 147456) {
      int j = i / 192, k = i % 192;
      int c = j >> 6, jc = j & 63, jb = jc >> 4, j15 = jc & 15;
      int kq = k >> 5, sl = (k & 31) >> 3, e7 = k & 7;
      w1f[(size_t)(((c*6 + kq)*4 + jb)*512) + (j15 + (sl << 4))*8 + e7] =
          __float2bfloat16(w1[(size_t)k*768 + j]);
      return;
    }
    i -= 147456;
    {
      int j = i / 192, d = i % 192;
      int c = j >> 6, ks = (j >> 5) & 1, l4 = (j >> 3) & 3, e = j & 7;
      int dn = d >> 4, l15 = d & 15;
      w2f[(size_t)((((c*2 + ks)*12 + dn)*64) + l4*16 + l15)*8 + e] =
          __float2bfloat16(w2[(size_t)j*192 + d]);
    }
    return;
  }
  {
    int row = (bid - 2448) * 4 + (threadIdx.x >> 6);
    int lane = threadIdx.x & 63;
    const float* xr = x + (size_t)row * 192;
    float v0 = xr[lane], v1 = xr[lane + 64], v2 = xr[lane + 128];
    float s = v0 + v1 + v2;
    #pragma unroll
    for (int o = 32; o; o >>= 1) s += __shfl_xor(s, o);
    float mu = s * (1.f / 192.f);
    float d0 = v0 - mu, d1 = v1 - mu, d2 = v2 - mu;
    float q = d0*d0 + d1*d1 + d2*d2;
    #pragma unroll
    for (int o = 32; o; o >>= 1) q += __shfl_xor(q, o);
    float rs = rsqrtf(q * (1.f / 192.f) + 1e-3f);
    bf16* orow = nb + (size_t)row * 192;
    orow[lane]       = __float2bfloat16(d0*rs*gamma1[lane]       + beta1[lane]);
    orow[lane + 64]  = __float2bfloat16(d1*rs*gamma1[lane + 64]  + beta1[lane + 64]);
    orow[lane + 128] = __float2bfloat16(d2*rs*gamma1[lane + 128] + beta1[lane + 128]);
  }
}

// ---------------- QKV GEMM, 128x64 tile, 4 waves. Col-blocks are uniformly q/k/MT ----------
__global__ __launch_bounds__(256) void gemm_qkv(
    const bf16* __restrict__ A, const bf16* __restrict__ BT,
    u8* __restrict__ q_out, u8* __restrict__ k_out, u8* __restrict__ mt_out)
{
  const int K = 192;
  const int tid = threadIdx.x, lane = tid & 63, wid = tid >> 6;
  const int l15 = lane & 15, l4 = lane >> 4;
  const int wm = wid >> 1, wn = wid & 1;
  const int row0 = blockIdx.y * 128, col0 = blockIdx.x * 64;
  const int sel0 = col0 / 576;                 // block-uniform: 0=q, 1=k, 2=MT
  __shared__ __align__(16) bf16 As[2][128 * 32];
  __shared__ __align__(16) bf16 Bs[2][64 * 32];
  f32x4 acc[4][2] = {};

#define STAGE(buf_, kt_) do { \
    const bf16* Ab_ = A + (size_t)row0 * K + (kt_) * 32; \
    int c0_ = tid, r0_ = c0_ >> 2, cc0_ = (c0_ & 3) << 3; \
    gld_lds16(Ab_ + (size_t)r0_ * K + cc0_, &As[buf_][c0_ * 8]); \
    int c1_ = tid + 256, r1_ = c1_ >> 2, cc1_ = (c1_ & 3) << 3; \
    gld_lds16(Ab_ + (size_t)r1_ * K + cc1_, &As[buf_][c1_ * 8]); \
    const bf16* Bb_ = BT + (size_t)col0 * K + (kt_) * 32; \
    gld_lds16(Bb_ + (size_t)(tid >> 2) * K + ((tid & 3) << 3), &Bs[buf_][tid * 8]); \
  } while (0)

  STAGE(0, 0);
  for (int kt = 0; kt < 6; ++kt) {
    __syncthreads();
    const int buf = kt & 1;
    if (kt + 1 < 6) STAGE(buf ^ 1, kt + 1);
    const int koff = l4 * 8;
    bf16x8 af[4], bfr[2];
    #pragma unroll
    for (int m = 0; m < 4; ++m)
      af[m] = *(const bf16x8*)&As[buf][(wm*64 + m*16 + l15)*32 + koff];
    #pragma unroll
    for (int n = 0; n < 2; ++n)
      bfr[n] = *(const bf16x8*)&Bs[buf][(wn*32 + n*16 + l15)*32 + koff];
    if (sel0 < 2) {
      #pragma unroll
      for (int m = 0; m < 4; ++m)
        #pragma unroll
        for (int n = 0; n < 2; ++n)
          acc[m][n] = __builtin_amdgcn_mfma_f32_16x16x32_bf16(bfr[n], af[m], acc[m][n], 0, 0, 0);
    } else {
      #pragma unroll
      for (int m = 0; m < 4; ++m)
        #pragma unroll
        for (int n = 0; n < 2; ++n)
          acc[m][n] = __builtin_amdgcn_mfma_f32_16x16x32_bf16(af[m], bfr[n], acc[m][n], 0, 0, 0);
    }
  }
#undef STAGE

  if (sel0 < 2) {
    u8* dst = (sel0 == 0) ? q_out : k_out;
    #pragma unroll
    for (int m = 0; m < 4; ++m) {
      const int t = row0 + wm*64 + m*16 + l15;
      const int b = t >> 11, t2 = t & 2047;
      #pragma unroll
      for (int n = 0; n < 2; ++n) {
        const int c2 = (col0 - sel0*576) + wn*32 + n*16 + l4*4;
        const int h = c2 / 192, kd = c2 % 192;
        int pk = __builtin_amdgcn_cvt_pk_fp8_f32(acc[m][n][0], acc[m][n][1], 0, false);
        pk = __builtin_amdgcn_cvt_pk_fp8_f32(acc[m][n][2], acc[m][n][3], pk, true);
        const size_t fo = ((((size_t)b*64 + (t2>>5))*3 + h)*6 + (kd>>5))*1024
                        + (((t2>>4)&1))*512
                        + (((t2&15) + (((kd>>3)&3)<<4))<<3) + (kd&7);
        *(unsigned*)&dst[fo] = (unsigned)pk;
      }
    }
  } else {
    const int rbase = row0 + wm * 64;
    const int cbase = col0 + wn * 32;
    #pragma unroll
    for (int m = 0; m < 4; ++m) {
      #pragma unroll
      for (int n = 0; n < 2; ++n) {
        const int col = cbase + n*16 + l15;
        const int rtop = rbase + m*16 + (l4 << 2);
        const int b = rtop >> 11, t_ = rtop & 2047;
        const int c2 = col % 576;
        const int h = c2 / 192, kd = c2 % 192;
        int pk = __builtin_amdgcn_cvt_pk_fp8_f32(acc[m][n][0], acc[m][n][1], 0, false);
        pk = __builtin_amdgcn_cvt_pk_fp8_f32(acc[m][n][2], acc[m][n][3], pk, true);
        const size_t fo = ((((size_t)b*64 + (t_>>5))*3 + h)*12 + (kd>>4))*512
                        + (((kd&15) + (((t_>>3)&3)<<4))<<3) + (t_&4);
        *(unsigned*)&mt_out[fo] = (unsigned)pk;
      }
    }
  }
}

// ------- fused attention + LN2 + MLP (MLP software-pipelined, 1 barrier/chunk) -------
__global__ __launch_bounds__(256, 2) void attn_k(
    const u8* __restrict__ q, const u8* __restrict__ kf,
    const u8* __restrict__ MT, const float* __restrict__ pre_w,
    const float* __restrict__ x, const float* __restrict__ gamma2,
    const float* __restrict__ beta2, const bf16* __restrict__ w1f,
    const bf16* __restrict__ w2f, const float* __restrict__ b1,
    const float* __restrict__ b2, float* __restrict__ out)
{
  const int tid = threadIdx.x, lane = tid & 63, wv = tid >> 6;
  const int l15 = lane & 15, l4 = lane >> 4;
  const int tq = wv & 1, sq = wv >> 1;
  const int bid = blockIdx.x;
  const int b = bid & 7;                 // XCD-local batch
  const int tt = bid >> 3;
  const int t0 = tt * 32;

  // Phase-aliased LDS: attn{Ks 2x18432 @0, Ps 2x3072 @36864} |
  // mlp{N2f 12288 @0, Bs dbuf 2x24576 @12288, Hf dbuf 2x4096 @61440}.
  __shared__ __align__(16) u8 S[69632];
  __shared__ float rlPart[2][3][32];
  __shared__ float lnS[4][32][2];
  u8* KsP = S;
  u8* PsP = S + 36864;
  bf16* N2 = (bf16*)S;                 // frag-linear A: [kq(6)*2+rblk][512]
  bf16* BsP = (bf16*)(S + 12288);      // frag-linear B dbuf: [buf][kq*4+jb][512]
  bf16* HfP = (bf16*)(S + 61440);      // frag-linear A dbuf: [buf][ks*2+rblk][512]

  const u8* qfb = q + ((size_t)b*64 + tt) * 18432;
  long qf[3][6];
  #pragma unroll
  for (int h = 0; h < 3; ++h)
    #pragma unroll
    for (int kq = 0; kq < 6; ++kq)
      qf[h][kq] = *(const long*)(qfb + ((h*6 + kq)*2 + tq)*512 + lane*8);

  f32x2 pwf2[9];
  #pragma unroll
  for (int i = 0; i < 9; ++i) {
    const float v = pre_w[i] * 0.07216878364870323f * 1.44269504088896f;
    pwf2[i][0] = v; pwf2[i][1] = v;
  }

  f32x4 acc[3][2][3] = {};
  float sgacc[3] = {0.f, 0.f, 0.f};
  const int trow = tq*16 + l15;
  const int psw = (l15 >> 2) & 3;
  const int pwr = (((sq*2 + (l4 >> 1)) ^ psw) << 3) + ((l4 & 1) << 2);
  const int prd = (l4 ^ psw) << 3;

  const u8* kfb = kf + (size_t)b * 64 * 18432;
  const u8* mtb = MT + (size_t)b * 64 * 18432;

#define STAGEK(buf_, st_) do { \
    const u8* kb_ = kfb + (size_t)(st_) * 18432; \
    _Pragma("unroll") \
    for (int i_ = 0; i_ < 5; ++i_) { \
      const int L_ = i_ * 256 + tid; \
      if (L_ < 1152) gld_lds16(kb_ + L_*16, KsP + (buf_)*18432 + L_*16); \
    } \
  } while (0)

#define LOADMF(MF_, st_) do { \
    const u8* mb_ = mtb + (size_t)(st_) * 18432 + wv*3*512 + lane*8; \
    _Pragma("unroll") \
    for (int g_ = 0; g_ < 3; ++g_) \
      _Pragma("unroll") \
      for (int n_ = 0; n_ < 3; ++n_) \
        MF_[g_][n_] = *(const long*)(mb_ + (g_*12 + n_)*512); \
  } while (0)

#define PV(stm1_, MF_) do { \
    const int bp_ = (stm1_) & 1; \
    __builtin_amdgcn_s_setprio(1); \
    _Pragma("unroll") \
    for (int g_ = 0; g_ < 3; ++g_) \
      _Pragma("unroll") \
      for (int m_ = 0; m_ < 2; ++m_) { \
        const long pf_ = *(const long*)(PsP + bp_*3072 + g_*1024 + (m_*16 + l15)*32 + prd); \
        _Pragma("unroll") \
        for (int n_ = 0; n_ < 3; ++n_) \
          acc[g_][m_][n_] = __builtin_amdgcn_mfma_f32_16x16x32_fp8_fp8(pf_, MF_[g_][n_], acc[g_][m_][n_], 0, 0, 0); \
      } \
    __builtin_amdgcn_s_setprio(0); \
  } while (0)

#define QKSM(st_) do { \
    const int bq_ = (st_) & 1; \
    f32x4 sacc0 = {}, sacc1 = {}, sacc2 = {}; \
    __builtin_amdgcn_s_setprio(1); \
    _Pragma("unroll") \
    for (int kq_ = 0; kq_ < 6; ++kq_) { \
      const long kf0_ = *(const long*)(KsP + bq_*18432 + (((0*6 + kq_)*2 + sq)*512) + lane*8); \
      sacc0 = __builtin_amdgcn_mfma_f32_16x16x32_fp8_fp8(kf0_, qf[0][kq_], sacc0, 0, 0, 0); \
      const long kf1_ = *(const long*)(KsP + bq_*18432 + (((1*6 + kq_)*2 + sq)*512) + lane*8); \
      sacc1 = __builtin_amdgcn_mfma_f32_16x16x32_fp8_fp8(kf1_, qf[1][kq_], sacc1, 0, 0, 0); \
      const long kf2_ = *(const long*)(KsP + bq_*18432 + (((2*6 + kq_)*2 + sq)*512) + lane*8); \
      sacc2 = __builtin_amdgcn_mfma_f32_16x16x32_fp8_fp8(kf2_, qf[2][kq_], sacc2, 0, 0, 0); \
    } \
    __builtin_amdgcn_s_setprio(0); \
    f32x2 p0a = {sacc0[0], sacc0[1]}, p0b = {sacc0[2], sacc0[3]}; \
    f32x2 p1a = {sacc1[0], sacc1[1]}, p1b = {sacc1[2], sacc1[3]}; \
    f32x2 p2a = {sacc2[0], sacc2[1]}, p2b = {sacc2[2], sacc2[3]}; \
    _Pragma("unroll") \
    for (int g_ = 0; g_ < 3; ++g_) { \
      f32x2 va = pk_mul(p0a, pwf2[g_]); \
      va = pk_fma(p1a, pwf2[3+g_], va); \
      va = pk_fma(p2a, pwf2[6+g_], va); \
      f32x2 vb = pk_mul(p0b, pwf2[g_]); \
      vb = pk_fma(p1b, pwf2[3+g_], vb); \
      vb = pk_fma(p2b, pwf2[6+g_], vb); \
      float e0_ = exp2f(va[0]), e1_ = exp2f(va[1]); \
      float e2_ = exp2f(vb[0]), e3_ = exp2f(vb[1]); \
      sgacc[g_] += (e0_ + e1_) + (e2_ + e3_); \
      int pk_ = __builtin_amdgcn_cvt_pk_fp8_f32(e0_, e1_, 0, false); \
      pk_ = __builtin_amdgcn_cvt_pk_fp8_f32(e2_, e3_, pk_, true); \
      *(unsigned*)(PsP + bq_*3072 + g_*1024 + trow*32 + pwr) = (unsigned)pk_; \
    } \
  } while (0)

#define STAGEB(buf_, c_) do { \
    const u8* wsrc_ = (const u8*)w1f + (size_t)(c_) * 24576; \
    _Pragma("unroll") \
    for (int i_ = 0; i_ < 6; ++i_) { \
      const int L_ = i_ * 256 + tid; \
      gld_lds16(wsrc_ + L_*16, (u8*)BsP + (buf_)*24576 + L_*16); \
    } \
  } while (0)

#define LOADWF(WF_, c_) do { \
    _Pragma("unroll") \
    for (int n_ = 0; n_ < 3; ++n_) \
      _Pragma("unroll") \
      for (int ks_ = 0; ks_ < 2; ++ks_) \
        WF_[n_][ks_] = *(const bf16x8*)(w2f + (size_t)(((((c_)*2 + ks_)*12) + wv*3 + n_)*64 + lane)*8); \
  } while (0)

  const int wmm = wv >> 1, wnn = wv & 1;

#define MGEMM1(c_) do { \
    f32x4 sacc[2] = {}; \
    _Pragma("unroll") \
    for (int kq_ = 0; kq_ < 6; ++kq_) { \
      const bf16x8 af_ = *(const bf16x8*)&N2[((kq_*2 + wmm)*512) + lane*8]; \
      _Pragma("unroll") \
      for (int n_ = 0; n_ < 2; ++n_) { \
        const bf16x8 bfr_ = *(const bf16x8*)&BsP[((c_)&1)*12288 + ((kq_*4 + wnn*2 + n_)*512) + lane*8]; \
        sacc[n_] = __builtin_amdgcn_mfma_f32_16x16x32_bf16(af_, bfr_, sacc[n_], 0, 0, 0); \
      } \
    } \
    _Pragma("unroll") \
    for (int n_ = 0; n_ < 2; ++n_) { \
      const int jc_ = wnn*32 + n_*16 + l15; \
      const float bv_ = b1[(c_)*64 + jc_]; \
      const int sl_ = (jc_ & 31) >> 3, e7_ = jc_ & 7; \
      _Pragma("unroll") \
      for (int jr_ = 0; jr_ < 4; ++jr_) { \
        const int r15_ = l4*4 + jr_; \
        const float u_ = sacc[n_][jr_] + bv_; \
        const float g_ = 0.5f * u_ * (1.f + erff(u_ * 0.70710678118654752f)); \
        HfP[((c_)&1)*2048 + ((wnn*2 + wmm)*512) + ((r15_ + (sl_ << 4)) << 3) + e7_] = __float2bfloat16(g_); \
      } \
    } \
  } while (0)

#define MGEMM2(WF_, hbuf_) do { \
    _Pragma("unroll") \
    for (int ks_ = 0; ks_ < 2; ++ks_) { \
      bf16x8 ha_[2]; \
      _Pragma("unroll") \
      for (int m_ = 0; m_ < 2; ++m_) \
        ha_[m_] = *(const bf16x8*)&HfP[(hbuf_)*2048 + ((ks_*2 + m_)*512) + lane*8]; \
      _Pragma("unroll") \
      for (int m_ = 0; m_ < 2; ++m_) \
        _Pragma("unroll") \
        for (int n_ = 0; n_ < 3; ++n_) \
          macc[m_][n_] = __builtin_amdgcn_mfma_f32_16x16x32_bf16(ha_[m_], WF_[n_][ks_], macc[m_][n_], 0, 0, 0); \
    } \
  } while (0)

  long mfA[3][3], mfB[3][3];

  // ======== attention phase (R13 structure) ========
  STAGEK(0, 0);
  __syncthreads();
  STAGEK(1, 1);
  LOADMF(mfA, 0);
  QKSM(0);
  for (int st = 1; st < 63; st += 2) {
    __syncthreads();
    STAGEK((st + 1) & 1, st + 1);
    LOADMF(mfB, st);
    PV(st - 1, mfA);
    QKSM(st);
    __syncthreads();
    if (st + 2 < 64) STAGEK((st + 2) & 1, st + 2);
    LOADMF(mfA, st + 1);
    PV(st, mfB);
    QKSM(st + 1);
  }
  __syncthreads();
  LOADMF(mfB, 63);
  PV(62, mfA);
  QKSM(63);
  __syncthreads();
  PV(63, mfB);            // reads Ps[1] @39936+ only
  STAGEB(0, 0);           // writes Bs[0] @12288..36863 (Ks dead, disjoint from Ps[1])
  #pragma unroll
  for (int g = 0; g < 3; ++g) {
    float s = sgacc[g];
    s += __shfl_xor(s, 16);
    s += __shfl_xor(s, 32);
    if (l4 == 0) rlPart[sq][g][trow] = s;
  }
  // x prefetch: residual loads issued under the barrier wait
  float xv[2][3][4];
  #pragma unroll
  for (int m = 0; m < 2; ++m)
    #pragma unroll
    for (int n = 0; n < 3; ++n) {
      const int d = wv*48 + n*16 + l15;
      #pragma unroll
      for (int j = 0; j < 4; ++j)
        xv[m][n][j] = x[((size_t)b*2048 + t0 + m*16 + l4*4 + j)*192 + d];
    }
  __syncthreads();

  // resid = x + attn (kept in regs), LN2 partials
  float ovv[2][3][4];
  #pragma unroll
  for (int m = 0; m < 2; ++m) {
    #pragma unroll
    for (int j = 0; j < 4; ++j) {
      const int row = m*16 + l4*4 + j;
      float rlv[3];
      #pragma unroll
      for (int g = 0; g < 3; ++g)
        rlv[g] = 1.f / (rlPart[0][g][row] + rlPart[1][g][row]);
      float s = 0.f, ss = 0.f;
      #pragma unroll
      for (int n = 0; n < 3; ++n) {
        const float ov = xv[m][n][j] + rlv[0]*acc[0][m][n][j] + rlv[1]*acc[1][m][n][j]
                                     + rlv[2]*acc[2][m][n][j];
        ovv[m][n][j] = ov;
        s += ov; ss += ov*ov;
      }
      #pragma unroll
      for (int o = 1; o < 16; o <<= 1) { s += __shfl_xor(s, o); ss += __shfl_xor(ss, o); }
      if (l15 == 0) { lnS[wv][row][0] = s; lnS[wv][row][1] = ss; }
    }
  }
  __syncthreads();

  // LN2 -> N2 (LDS, fragment-linear A layout)
  {
    float gmL[3], btL[3];
    #pragma unroll
    for (int n = 0; n < 3; ++n) {
      const int d = wv*48 + n*16 + l15;
      gmL[n] = gamma2[d]; btL[n] = beta2[d];
    }
    #pragma unroll
    for (int m = 0; m < 2; ++m) {
      #pragma unroll
      for (int j = 0; j < 4; ++j) {
        const int row = m*16 + l4*4 + j;
        const float ts  = lnS[0][row][0] + lnS[1][row][0] + lnS[2][row][0] + lnS[3][row][0];
        const float tss = lnS[0][row][1] + lnS[1][row][1] + lnS[2][row][1] + lnS[3][row][1];
        const float mu = ts * (1.f / 192.f);
        const float rs = rsqrtf(tss * (1.f / 192.f) - mu*mu + 1e-3f);
        #pragma unroll
        for (int n = 0; n < 3; ++n) {
          const int d = wv*48 + n*16 + l15;
          N2[(((d>>5)*2 + m)*512) + (((row&15) + (((d&31)>>3)<<4))<<3) + (d&7)] =
              __float2bfloat16((ovv[m][n][j] - mu) * rs * gmL[n] + btL[n]);
        }
      }
    }
  }
  __syncthreads();   // N2 + Bs[0] ready

  // ======== MLP phase: pipelined, 1 barrier/chunk ========
  f32x4 macc[2][3] = {};
  bf16x8 wfA[3][2], wfB[3][2];

  // prologue: chunk 0
  STAGEB(1, 1);
  LOADWF(wfA, 0);
  MGEMM1(0);                         // -> Hf[0]
  __syncthreads();
  // pairs: chunks (1,2), (3,4), (5,6), (7,8), (9,10)
  for (int c = 1; c < 11; c += 2) {
    STAGEB((c + 1) & 1, c + 1);      // even chunk -> buf0
    LOADWF(wfB, c);
    MGEMM2(wfA, (c - 1) & 1);        // GEMM2 chunk c-1 (even, wfA)
    MGEMM1(c);                       // -> Hf[1]
    __syncthreads();
    if (c + 2 < 12) STAGEB((c + 2) & 1, c + 2);
    LOADWF(wfA, c + 1);
    MGEMM2(wfB, c & 1);              // GEMM2 chunk c (odd, wfB)
    MGEMM1(c + 1);                   // -> Hf[0]
    __syncthreads();
  }
  // tail: chunk 11
  LOADWF(wfB, 11);
  MGEMM2(wfA, 0);                    // GEMM2 chunk 10 (Hf[0], wfA)
  MGEMM1(11);                        // -> Hf[1]
  __syncthreads();
  MGEMM2(wfB, 1);                    // GEMM2 chunk 11

  // single out write: resid + mlp + b2
  #pragma unroll
  for (int n = 0; n < 3; ++n) {
    const int d = wv*48 + n*16 + l15;
    const float b2v = b2[d];
    #pragma unroll
    for (int m = 0; m < 2; ++m) {
      #pragma unroll
      for (int jr = 0; jr < 4; ++jr) {
        const int row = m*16 + l4*4 + jr;
        const size_t idx = ((size_t)b*2048 + t0 + row)*192 + d;
        out[idx] = ovv[m][n][jr] + macc[m][n][jr] + b2v;
      }
    }
  }
#undef STAGEK
#undef LOADMF
#undef PV
#undef QKSM
#undef STAGEB
#undef LOADWF
#undef MGEMM1
#undef MGEMM2
}

// ---------------- host launcher ----------------
extern "C" void kernel_launch(void* const* d_in, const int* in_sizes, int n_in,
                              void* d_out, int out_size, void* d_ws, size_t ws_size,
                              hipStream_t stream)
{
  (void)in_sizes; (void)n_in; (void)out_size; (void)ws_size;
  const float* x      = (const float*)d_in[0];
  const float* gamma1 = (const float*)d_in[1];
  const float* beta1  = (const float*)d_in[2];
  const float* gamma2 = (const float*)d_in[3];
  const float* beta2  = (const float*)d_in[4];
  const float* wq     = (const float*)d_in[5];
  const float* wk     = (const float*)d_in[6];
  const float* wv     = (const float*)d_in[7];
  const float* wo     = (const float*)d_in[8];
  const float* pre_w  = (const float*)d_in[9];
  const float* post_w = (const float*)d_in[10];
  const float* w1     = (const float*)d_in[11];
  const float* b1     = (const float*)d_in[12];
  const float* w2     = (const float*)d_in[13];
  const float* b2     = (const float*)d_in[14];
  float* out = (float*)d_out;

  uint8_t* base = (uint8_t*)d_ws;
  size_t off = 0;
  auto alloc = [&](size_t bytes) {
    uint8_t* r = base + off; off += (bytes + 255) & ~(size_t)255; return r;
  };
  bf16* nb      = (bf16*)alloc((size_t)16384 * 192 * 2);    // n1
  u8*   qb      = (u8*)alloc((size_t)9437184);              // Q frag
  u8*   kb      = (u8*)alloc((size_t)9437184);              // K frag
  u8*   MTslab  = (u8*)alloc((size_t)9437184);              // MT frag
  bf16* WqkvT   = (bf16*)alloc((size_t)331776 * 2);         // rows 0..1151 q,k; 1152..1727 Wm
  bf16* w1f     = (bf16*)alloc((size_t)147456 * 2);         // w1 fragment-linear
  bf16* w2f     = (bf16*)alloc((size_t)147456 * 2);         // w2 fragment-linear

  setup_k<<<6544, 256, 0, stream>>>(x, gamma1, beta1, wq, wk, wv, wo, post_w, w1, w2,
                                    nb, WqkvT, w1f, w2f);
  gemm_qkv<<<dim3(27, 128, 1), 256, 0, stream>>>(nb, WqkvT, qb, kb, MTslab);
  attn_k<<<512, 256, 0, stream>>>(qb, kb, MTslab, pre_w, x, gamma2, beta2,
                                  w1f, w2f, b1, b2, out);
}